// Round 4
// baseline (199.860 us; speedup 1.0000x reference)
//
#include <hip/hip_runtime.h>

// Problem: B=2, S=2048, D=1024, H=16, HD=64. fp32 in/out.
// Pipeline exploits head-summed K/V: k_sum = x @ (sum_h Wk_h)^T + sum_h bk_h.
//  1. prep_all:     x, Wq, Wout -> f16; head-reduced Wk/Wv (128x1024) + biases
//  2. gemm128<0>:   Q = x @ Wq^T + bq          (4096x1024x1024) -> f16
//  3. gemm_kv:      kv = x @ Wred^T + bred     (4096x128x1024) -> kb + vtb(V^T)
//  4. flash_attn4:  S^T formulation, 2 s per wave (shared K/V frags), DMA staging
//  5. gemm128<1>:   out = ao @ Wout^T + bout   (4096x1024x1024) -> f32

#define S_LEN 2048
#define DIM 1024

using floatx4 = __attribute__((ext_vector_type(4))) float;
using halfx8  = __attribute__((ext_vector_type(8))) _Float16;
using halfx4  = __attribute__((ext_vector_type(4))) _Float16;

__device__ __forceinline__ floatx4 mfma16(halfx8 a, halfx8 b, floatx4 c) {
  return __builtin_amdgcn_mfma_f32_16x16x32_f16(a, b, c, 0, 0, 0);
}

// async global->LDS, 16B per lane; lds dst is wave-uniform base + lane*16
__device__ __forceinline__ void gll16(const void* g, void* l) {
  __builtin_amdgcn_global_load_lds(
      (const __attribute__((address_space(1))) void*)g,
      (__attribute__((address_space(3))) void*)l, 16, 0, 0);
}

// ---------------- prep: conversions + head-reduced K/V weights ----------------
__global__ __launch_bounds__(256) void prep_all(
    const float* __restrict__ x, const float* __restrict__ wqkv,
    const float* __restrict__ bqkv, const float* __restrict__ wout,
    _Float16* __restrict__ xb, _Float16* __restrict__ wqb,
    _Float16* __restrict__ woutb, _Float16* __restrict__ wredb,
    float* __restrict__ bred) {
  int bx = blockIdx.x;
  if (bx < 6144) {
    size_t i4 = ((size_t)bx * 256 + threadIdx.x) * 4;
    const float* src;
    _Float16* dst;
    size_t off;
    if (i4 < 4194304) { src = x; dst = xb; off = i4; }
    else if (i4 < 5242880) { src = wqkv; dst = wqb; off = i4 - 4194304; }
    else { src = wout; dst = woutb; off = i4 - 5242880; }
    float4 v = *(const float4*)(src + off);
    halfx4 o;
    o[0] = (_Float16)v.x; o[1] = (_Float16)v.y;
    o[2] = (_Float16)v.z; o[3] = (_Float16)v.w;
    *(halfx4*)(dst + off) = o;
  } else {
    int gid = (bx - 6144) * 256 + threadIdx.x;  // 131072 threads
    int c = gid >> 10, j = gid & 1023;
    int row0 = (c < 64) ? (1024 + c) : (2048 + c - 64);
    float s = 0.f;
#pragma unroll
    for (int h = 0; h < 16; ++h) s += wqkv[(size_t)(row0 + h * 64) * 1024 + j];
    wredb[gid] = (_Float16)s;
    if (gid < 128) {
      int b0 = (gid < 64) ? (1024 + gid) : (2048 + gid - 64);
      float sb = 0.f;
#pragma unroll
      for (int h = 0; h < 16; ++h) sb += bqkv[b0 + h * 64];
      bred[gid] = sb;
    }
  }
}

// ---------------- GEMM 64Mx128N, BK=64, global_load_lds staging ----------------
template <int MODE>
__global__ __launch_bounds__(256, 4) void gemm128(
    const _Float16* __restrict__ A, const _Float16* __restrict__ W,
    const float* __restrict__ bias, void* __restrict__ Cv, int K, int ldc) {
  __shared__ _Float16 As[64][64];    // 8 KB
  __shared__ _Float16 Ws[128][64];   // 16 KB
  int tid = threadIdx.x;
  int lane = tid & 63, w = tid >> 6, ln = lane & 15, q4 = lane >> 4;
  int m0 = blockIdx.y * 64, n0 = blockIdx.x * 128;
  int rA = lane >> 3;                        // row-in-chunk 0..7
  int gA = ((lane & 7) ^ rA) * 8;            // swizzled global col-half
  const _Float16* agp = A + (size_t)(m0 + 16 * w + rA) * K + gA;
  const _Float16* wgp = W + (size_t)(n0 + 32 * w + rA) * K + gA;
  floatx4 acc[4][2] = {};
  for (int kt = 0; kt < K; kt += 64) {
    __syncthreads();
#pragma unroll
    for (int j = 0; j < 2; ++j)
      gll16(agp + (size_t)(8 * j) * K + kt, &As[16 * w + 8 * j][0]);
#pragma unroll
    for (int j = 0; j < 4; ++j)
      gll16(wgp + (size_t)(8 * j) * K + kt, &Ws[32 * w + 8 * j][0]);
    __syncthreads();
#pragma unroll
    for (int kh = 0; kh < 2; ++kh) {
      int sw = ((q4 + 4 * kh) ^ (ln & 7)) * 8;
      halfx8 bf[2];
#pragma unroll
      for (int ni = 0; ni < 2; ++ni)
        bf[ni] = *(const halfx8*)&Ws[w * 32 + ni * 16 + ln][sw];
#pragma unroll
      for (int mi = 0; mi < 4; ++mi) {
        halfx8 af = *(const halfx8*)&As[mi * 16 + ln][sw];
#pragma unroll
        for (int ni = 0; ni < 2; ++ni)
          acc[mi][ni] = mfma16(af, bf[ni], acc[mi][ni]);
      }
    }
  }
#pragma unroll
  for (int ni = 0; ni < 2; ++ni) {
    int col = n0 + w * 32 + ni * 16 + ln;
    float bv = bias[col];
#pragma unroll
    for (int mi = 0; mi < 4; ++mi)
#pragma unroll
      for (int i = 0; i < 4; ++i) {
        int row = m0 + mi * 16 + q4 * 4 + i;
        float v = acc[mi][ni][i] + bv;
        if constexpr (MODE == 0)
          ((_Float16*)Cv)[(size_t)row * ldc + col] = (_Float16)v;
        else
          ((float*)Cv)[(size_t)row * ldc + col] = v;
      }
  }
}

// ---------------- KV GEMM (64x64 tile): kb + vtb(V^T) epilogue ----------------
__global__ __launch_bounds__(256) void gemm_kv(
    const _Float16* __restrict__ A, const _Float16* __restrict__ W,
    const float* __restrict__ bias, _Float16* __restrict__ kbo,
    _Float16* __restrict__ vto, int K) {
  __shared__ _Float16 As[64][72];
  __shared__ _Float16 Ws[64][72];
  int tid = threadIdx.x;
  int lane = tid & 63, w = tid >> 6, ln = lane & 15, q4 = lane >> 4;
  int m0 = blockIdx.y * 64, n0 = blockIdx.x * 64;
  int sr = tid >> 2, sc = (tid & 3) * 16;
  const _Float16* ap = A + (size_t)(m0 + sr) * K + sc;
  const _Float16* wp = W + (size_t)(n0 + sr) * K + sc;
  floatx4 acc[4] = {};
  for (int kt = 0; kt < K; kt += 64) {
    __syncthreads();
    *(halfx8*)&As[sr][sc]     = *(const halfx8*)(ap + kt);
    *(halfx8*)&As[sr][sc + 8] = *(const halfx8*)(ap + kt + 8);
    *(halfx8*)&Ws[sr][sc]     = *(const halfx8*)(wp + kt);
    *(halfx8*)&Ws[sr][sc + 8] = *(const halfx8*)(wp + kt + 8);
    __syncthreads();
#pragma unroll
    for (int ks = 0; ks < 2; ++ks) {
      halfx8 af = *(const halfx8*)&As[w * 16 + ln][ks * 32 + q4 * 8];
#pragma unroll
      for (int n = 0; n < 4; ++n) {
        halfx8 bf = *(const halfx8*)&Ws[n * 16 + ln][ks * 32 + q4 * 8];
        acc[n] = mfma16(af, bf, acc[n]);
      }
    }
  }
#pragma unroll
  for (int n = 0; n < 4; ++n) {
    int col = n0 + n * 16 + ln;
    float bv = bias[col];
#pragma unroll
    for (int i = 0; i < 4; ++i) {
      int row = m0 + w * 16 + q4 * 4 + i;
      float v = acc[n][i] + bv;
      if (col < 64) {
        kbo[(size_t)row * 64 + col] = (_Float16)v;
      } else {
        int bb = row >> 11, s = row & 2047;
        vto[(size_t)((bb << 6) + (col - 64)) * S_LEN + s] = (_Float16)v;
      }
    }
  }
}

// ---------------- flash v4: S^T formulation, 2 s per wave ----------------
// Per-s softmax + PV step; K/V frags and staging shared between the wave's 2 s.
__device__ __forceinline__ void flash_step(
    floatx4 sf[4], bool last, int t0, int s, int q4, int ln,
    float& m_run, float& l_run, floatx4 oacc[4], _Float16* Pw,
    const halfx8 av0[4], const halfx8 av1[4]) {
  const float sc_log2 = 0.18033688011112042f;  // (1/sqrt(64)) * log2(e)
  if (last) {
#pragma unroll
    for (int tf = 0; tf < 4; ++tf)
#pragma unroll
      for (int i = 0; i < 4; ++i) {
        int t = t0 + tf * 16 + q4 * 4 + i;
        sf[tf][i] = (t > s) ? -1e30f : sf[tf][i] * sc_log2;
      }
  } else {
#pragma unroll
    for (int tf = 0; tf < 4; ++tf)
#pragma unroll
      for (int i = 0; i < 4; ++i) sf[tf][i] *= sc_log2;
  }
  float tm = fmaxf(fmaxf(sf[0][0], sf[0][1]), fmaxf(sf[0][2], sf[0][3]));
#pragma unroll
  for (int tf = 1; tf < 4; ++tf)
    tm = fmaxf(tm, fmaxf(fmaxf(sf[tf][0], sf[tf][1]),
                         fmaxf(sf[tf][2], sf[tf][3])));
  tm = fmaxf(tm, __shfl_xor(tm, 16));
  tm = fmaxf(tm, __shfl_xor(tm, 32));
  float mn = fmaxf(m_run, tm);
  float alpha = exp2f(m_run - mn);
  m_run = mn;
  float rs = 0.f;
#pragma unroll
  for (int tf = 0; tf < 4; ++tf) {
    float p0 = exp2f(sf[tf][0] - mn), p1 = exp2f(sf[tf][1] - mn);
    float p2 = exp2f(sf[tf][2] - mn), p3 = exp2f(sf[tf][3] - mn);
    rs += (p0 + p1) + (p2 + p3);
    halfx4 pk;
    pk[0] = (_Float16)p0; pk[1] = (_Float16)p1;
    pk[2] = (_Float16)p2; pk[3] = (_Float16)p3;
    *(halfx4*)&Pw[ln * 72 + tf * 16 + q4 * 4] = pk;
  }
  rs += __shfl_xor(rs, 16);
  rs += __shfl_xor(rs, 32);
  l_run = l_run * alpha + rs;
  halfx8 bp0 = *(const halfx8*)&Pw[ln * 72 + q4 * 8];
  halfx8 bp1 = *(const halfx8*)&Pw[ln * 72 + 32 + q4 * 8];
#pragma unroll
  for (int n2 = 0; n2 < 4; ++n2) {
#pragma unroll
    for (int i = 0; i < 4; ++i) oacc[n2][i] *= alpha;
    oacc[n2] = mfma16(av0[n2], bp0, oacc[n2]);
    oacc[n2] = mfma16(av1[n2], bp1, oacc[n2]);
  }
}

// Block = 4 waves x 2 s = 8 consecutive s (s0 = 8c, so floor((s0+7)/64) ==
// floor(s0/64): uniform nt, mask needed only on the final tile -- provable).
// Grid 512 (c,b), LPT order. K/V staged via gll16 with XOR swizzle (pitch 64).
__global__ __launch_bounds__(256, 2) void flash_attn4(
    const _Float16* __restrict__ Qb, const _Float16* __restrict__ kb,
    const _Float16* __restrict__ vtb, _Float16* __restrict__ aob) {
  __shared__ _Float16 Ks[64][64];     // K tile [t][d], XOR-swizzled groups
  __shared__ _Float16 Vt[64][64];     // V^T tile [d][t], XOR-swizzled
  __shared__ _Float16 Ps[4][16][72];  // per-wave P[h][t], pitch 144 B
  int tid = threadIdx.x;
  int lane = tid & 63, w = tid >> 6, ln = lane & 15, q4 = lane >> 4;
  int idx = 511 - (int)blockIdx.x;    // longest chunks first
  int c = idx >> 1, b = idx & 1;
  int s0 = c * 8;
  int sA = s0 + w, sB = s0 + w + 4;
  size_t bS = (size_t)b * S_LEN;

  const _Float16* qpA = Qb + (bS + sA) * DIM + ln * 64 + q4 * 8;
  const _Float16* qpB = Qb + (bS + sB) * DIM + ln * 64 + q4 * 8;
  halfx8 bqA0 = *(const halfx8*)qpA, bqA1 = *(const halfx8*)(qpA + 32);
  halfx8 bqB0 = *(const halfx8*)qpB, bqB1 = *(const halfx8*)(qpB + 32);

  float mA = -1e30f, lA = 0.f, mB = -1e30f, lB = 0.f;
  floatx4 oA[4] = {}, oB[4] = {};

  // staging: this lane covers row w*16 + rr (+8 for 2nd call), group gg
  int rr = lane >> 3, gg = (lane & 7) ^ rr;
  const _Float16* kgp = kb + (bS + w * 16 + rr) * 64 + gg * 8;
  const _Float16* vgp = vtb + ((size_t)b * 64 + w * 16 + rr) * S_LEN + gg * 8;

  int swk0 = (q4 ^ (ln & 7)) * 8;         // frag-read swizzled cols, kh=0
  int swk1 = ((q4 + 4) ^ (ln & 7)) * 8;   // kh=1
  _Float16* Pw = &Ps[w][0][0];
  int nt = (s0 >> 6) + 1;

  for (int it = 0; it < nt; ++it) {
    int t0 = it << 6;
    __syncthreads();
    gll16(kgp + (size_t)t0 * 64,        &Ks[w * 16][0]);
    gll16(kgp + (size_t)t0 * 64 + 512,  &Ks[w * 16 + 8][0]);
    gll16(vgp + t0,                     &Vt[w * 16][0]);
    gll16(vgp + t0 + (size_t)8 * S_LEN, &Vt[w * 16 + 8][0]);
    __syncthreads();

    halfx8 ak0[4], ak1[4];
#pragma unroll
    for (int tf = 0; tf < 4; ++tf) {
      ak0[tf] = *(const halfx8*)&Ks[tf * 16 + ln][swk0];
      ak1[tf] = *(const halfx8*)&Ks[tf * 16 + ln][swk1];
    }
    floatx4 sfA[4], sfB[4];
#pragma unroll
    for (int tf = 0; tf < 4; ++tf) {
      floatx4 z = {};
      z = mfma16(ak0[tf], bqA0, z);
      sfA[tf] = mfma16(ak1[tf], bqA1, z);
      floatx4 z2 = {};
      z2 = mfma16(ak0[tf], bqB0, z2);
      sfB[tf] = mfma16(ak1[tf], bqB1, z2);
    }
    halfx8 av0[4], av1[4];
#pragma unroll
    for (int n2 = 0; n2 < 4; ++n2) {
      av0[n2] = *(const halfx8*)&Vt[n2 * 16 + ln][swk0];
      av1[n2] = *(const halfx8*)&Vt[n2 * 16 + ln][swk1];
    }
    bool last = (it == nt - 1);
    flash_step(sfA, last, t0, sA, q4, ln, mA, lA, oA, Pw, av0, av1);
    flash_step(sfB, last, t0, sB, q4, ln, mB, lB, oB, Pw, av0, av1);
  }
  // epilogue: O^T frag n2: h=ln, d=n2*16+q4*4+i
  float invA = 1.0f / lA, invB = 1.0f / lB;
#pragma unroll
  for (int n2 = 0; n2 < 4; ++n2) {
    halfx4 oa, ob;
#pragma unroll
    for (int i = 0; i < 4; ++i) {
      oa[i] = (_Float16)(oA[n2][i] * invA);
      ob[i] = (_Float16)(oB[n2][i] * invB);
    }
    *(halfx4*)(aob + (bS + sA) * DIM + ln * 64 + n2 * 16 + q4 * 4) = oa;
    *(halfx4*)(aob + (bS + sB) * DIM + ln * 64 + n2 * 16 + q4 * 4) = ob;
  }
}

extern "C" void kernel_launch(void* const* d_in, const int* in_sizes, int n_in,
                              void* d_out, int out_size, void* d_ws,
                              size_t ws_size, hipStream_t stream) {
  const float* x    = (const float*)d_in[0];
  const float* wqkv = (const float*)d_in[1];
  const float* bqkv = (const float*)d_in[2];
  const float* wout = (const float*)d_in[3];
  const float* bout = (const float*)d_in[4];
  float* out = (float*)d_out;
  char* ws = (char*)d_ws;
  _Float16* xb    = (_Float16*)(ws);                               // 8 MB
  _Float16* qb    = (_Float16*)(ws + (8u << 20));                  // 8 MB
  _Float16* aob   = (_Float16*)(ws + (16u << 20));                 // 8 MB
  _Float16* kb    = (_Float16*)(ws + (24u << 20));                 // 512 KB
  _Float16* vtb   = (_Float16*)(ws + (24u << 20) + (512u << 10));  // 512 KB
  _Float16* wqb   = (_Float16*)(ws + (25u << 20));                 // 2 MB
  _Float16* woutb = (_Float16*)(ws + (27u << 20));                 // 2 MB
  _Float16* wredb = (_Float16*)(ws + (29u << 20));                 // 256 KB
  float*    bred  = (float*)(ws + (29u << 20) + (256u << 10));

  hipLaunchKernelGGL(prep_all, dim3(6656), dim3(256), 0, stream,
                     x, wqkv, bqkv, wout, xb, wqb, woutb, wredb, bred);
  hipLaunchKernelGGL((gemm128<0>), dim3(8, 64), dim3(256), 0, stream,
                     xb, wqb, bqkv, (void*)qb, 1024, 1024);
  hipLaunchKernelGGL(gemm_kv, dim3(2, 64), dim3(256), 0, stream,
                     xb, wredb, bred, kb, vtb, 1024);
  hipLaunchKernelGGL(flash_attn4, dim3(512), dim3(256), 0, stream,
                     qb, kb, vtb, aob);
  hipLaunchKernelGGL((gemm128<1>), dim3(8, 64), dim3(256), 0, stream,
                     aob, woutb, bout, (void*)out, 1024, 1024);
}

// Round 5
// 180.869 us; speedup vs baseline: 1.1050x; 1.1050x over previous
//
#include <hip/hip_runtime.h>

// Problem: B=2, S=2048, D=1024, H=16, HD=64. fp32 in/out.
// Pipeline exploits head-summed K/V: k_sum = x @ (sum_h Wk_h)^T + sum_h bk_h.
//  1. prep_all:    x, Wout -> f16; wcomb = [Wq; Wred] f16 (1152x1024); bcomb
//  2. gemm_big<0>: [Q*scale | k_sum | v_sum^T] = x @ wcomb^T + bcomb  (N=1152)
//  3. flash_attn5: S^T formulation, 1 s/wave, grid 1024 LPT, DMA staging
//  4. gemm_big<1>: out = ao @ Wout^T + bout   (4096x1024x1024) -> f32

#define S_LEN 2048
#define DIM 1024

using floatx4 = __attribute__((ext_vector_type(4))) float;
using halfx8  = __attribute__((ext_vector_type(8))) _Float16;
using halfx4  = __attribute__((ext_vector_type(4))) _Float16;

__device__ __forceinline__ floatx4 mfma16(halfx8 a, halfx8 b, floatx4 c) {
  return __builtin_amdgcn_mfma_f32_16x16x32_f16(a, b, c, 0, 0, 0);
}

// async global->LDS, 16B per lane; lds dst is wave-uniform base + lane*16
__device__ __forceinline__ void gll16(const void* g, void* l) {
  __builtin_amdgcn_global_load_lds(
      (const __attribute__((address_space(1))) void*)g,
      (__attribute__((address_space(3))) void*)l, 16, 0, 0);
}

// ---------------- prep: conversions + combined weights ----------------
__global__ __launch_bounds__(256) void prep_all(
    const float* __restrict__ x, const float* __restrict__ wqkv,
    const float* __restrict__ bqkv, const float* __restrict__ wout,
    _Float16* __restrict__ xb, _Float16* __restrict__ wcomb,
    _Float16* __restrict__ woutb, float* __restrict__ bcomb) {
  int bx = blockIdx.x;
  if (bx < 6144) {
    size_t i4 = ((size_t)bx * 256 + threadIdx.x) * 4;
    const float* src;
    _Float16* dst;
    size_t off;
    if (i4 < 4194304) { src = x; dst = xb; off = i4; }
    else if (i4 < 5242880) { src = wqkv; dst = wcomb; off = i4 - 4194304; }
    else { src = wout; dst = woutb; off = i4 - 5242880; }
    float4 v = *(const float4*)(src + off);
    halfx4 o;
    o[0] = (_Float16)v.x; o[1] = (_Float16)v.y;
    o[2] = (_Float16)v.z; o[3] = (_Float16)v.w;
    *(halfx4*)(dst + off) = o;
  } else {
    int gid = (bx - 6144) * 256 + threadIdx.x;  // 131072 threads
    int c = gid >> 10, j = gid & 1023;
    int row0 = (c < 64) ? (1024 + c) : (2048 + c - 64);
    float s = 0.f;
#pragma unroll
    for (int h = 0; h < 16; ++h) s += wqkv[(size_t)(row0 + h * 64) * 1024 + j];
    wcomb[(size_t)1024 * 1024 + gid] = (_Float16)s;
    if (gid < 1024) bcomb[gid] = bqkv[gid];
    if (gid < 128) {
      int b0 = (gid < 64) ? (1024 + gid) : (2048 + gid - 64);
      float sb = 0.f;
#pragma unroll
      for (int h = 0; h < 16; ++h) sb += bqkv[b0 + h * 64];
      bcomb[1024 + gid] = sb;
    }
  }
}

// ---------------- gemm_big: 64M x 128N, BK=64, single barrier/step ----------------
// A double-buffered in LDS (gll16, XOR swizzle); W fragments loaded straight to
// registers, prefetched one K-step ahead (no W LDS, no second barrier).
// MODE 0: N=1152 fused epilogue -> qb (cols<1024, *softmax-scale), kb, vtb(V^T).
// MODE 1: N=1024, f32 out. Grid (M/64, N/128) with x=m so blocks sharing a
// W-slice (same y) are consecutive ids -> spread 8-per-XCD.
template <int MODE>
__global__ __launch_bounds__(256, 2) void gemm_big(
    const _Float16* __restrict__ A, const _Float16* __restrict__ W,
    const float* __restrict__ bias, void* __restrict__ Cv,
    _Float16* __restrict__ kbo, _Float16* __restrict__ vto) {
  const int K = 1024;
  __shared__ _Float16 As[2][64][64];  // 16 KB double-buffered
  int tid = threadIdx.x;
  int lane = tid & 63, w = tid >> 6, ln = lane & 15, q4 = lane >> 4;
  int m0 = blockIdx.x * 64, n0 = blockIdx.y * 128;
  int rA = lane >> 3;
  int gA = ((lane & 7) ^ rA) * 8;
  const _Float16* agp = A + (size_t)(m0 + 16 * w + rA) * K + gA;
  const _Float16* wfp = W + (size_t)(n0 + w * 32 + ln) * K + q4 * 8;
  floatx4 acc[4][2] = {};
  halfx8 bf[2][2], bfn[2][2];
  // prologue: stage As(0), load W(0)
  gll16(agp, &As[0][16 * w][0]);
  gll16(agp + (size_t)8 * K, &As[0][16 * w + 8][0]);
#pragma unroll
  for (int ni = 0; ni < 2; ++ni)
#pragma unroll
    for (int kh = 0; kh < 2; ++kh)
      bf[ni][kh] = *(const halfx8*)(wfp + (size_t)ni * 16 * K + kh * 32);
  __syncthreads();
  for (int kt = 0; kt < K; kt += 64) {
    int cur = (kt >> 6) & 1;
    if (kt + 64 < K) {
      gll16(agp + kt + 64, &As[cur ^ 1][16 * w][0]);
      gll16(agp + (size_t)8 * K + kt + 64, &As[cur ^ 1][16 * w + 8][0]);
#pragma unroll
      for (int ni = 0; ni < 2; ++ni)
#pragma unroll
        for (int kh = 0; kh < 2; ++kh)
          bfn[ni][kh] =
              *(const halfx8*)(wfp + (size_t)ni * 16 * K + kt + 64 + kh * 32);
    }
#pragma unroll
    for (int kh = 0; kh < 2; ++kh) {
      int sw = ((q4 + 4 * kh) ^ (ln & 7)) * 8;
#pragma unroll
      for (int mi = 0; mi < 4; ++mi) {
        halfx8 af = *(const halfx8*)&As[cur][mi * 16 + ln][sw];
#pragma unroll
        for (int ni = 0; ni < 2; ++ni)
          acc[mi][ni] = mfma16(af, bf[ni][kh], acc[mi][ni]);
      }
    }
    if (kt + 64 < K) {
#pragma unroll
      for (int ni = 0; ni < 2; ++ni)
#pragma unroll
        for (int kh = 0; kh < 2; ++kh) bf[ni][kh] = bfn[ni][kh];
    }
    __syncthreads();  // all waves done reading As[cur]; As[cur^1] gll16 drained
  }
  const float qscale = 0.18033688011112042f;  // (1/sqrt(64)) * log2(e)
#pragma unroll
  for (int ni = 0; ni < 2; ++ni) {
    int col = n0 + w * 32 + ni * 16 + ln;
    float bv = bias[col];
    if constexpr (MODE == 1) {
#pragma unroll
      for (int mi = 0; mi < 4; ++mi)
#pragma unroll
        for (int i = 0; i < 4; ++i) {
          int row = m0 + mi * 16 + q4 * 4 + i;
          ((float*)Cv)[(size_t)row * 1024 + col] = acc[mi][ni][i] + bv;
        }
    } else {
      if (col < 1024) {  // Q, pre-scaled for log2-domain softmax
#pragma unroll
        for (int mi = 0; mi < 4; ++mi)
#pragma unroll
          for (int i = 0; i < 4; ++i) {
            int row = m0 + mi * 16 + q4 * 4 + i;
            ((_Float16*)Cv)[(size_t)row * 1024 + col] =
                (_Float16)((acc[mi][ni][i] + bv) * qscale);
          }
      } else if (col < 1088) {  // k_sum
        int ck = col - 1024;
#pragma unroll
        for (int mi = 0; mi < 4; ++mi)
#pragma unroll
          for (int i = 0; i < 4; ++i) {
            int row = m0 + mi * 16 + q4 * 4 + i;
            kbo[(size_t)row * 64 + ck] = (_Float16)(acc[mi][ni][i] + bv);
          }
      } else {  // v_sum, transposed: vtb[(b*64+d)*S + s]
        int d = col - 1088;
#pragma unroll
        for (int mi = 0; mi < 4; ++mi) {
          int row0 = m0 + mi * 16 + q4 * 4;
          int bb = row0 >> 11, sps = row0 & 2047;
          halfx4 o;
#pragma unroll
          for (int i = 0; i < 4; ++i) o[i] = (_Float16)(acc[mi][ni][i] + bv);
          *(halfx4*)&vto[((size_t)((bb << 6) + d)) * S_LEN + sps] = o;
        }
      }
    }
  }
}

// ---------------- flash v5: S^T formulation, 1 s per wave ----------------
// Wave = one s, all 16 heads. Q pre-scaled (log2 domain) by the Q-GEMM, so
// non-last tiles need zero pre-softmax VALU; last tile is one cndmask.
// Grid 1024 LPT; gll16 XOR-swizzled K/V staging; Ps pitch 72 (2-way, free).
__global__ __launch_bounds__(256, 4) void flash_attn5(
    const _Float16* __restrict__ Qb, const _Float16* __restrict__ kb,
    const _Float16* __restrict__ vtb, _Float16* __restrict__ aob) {
  __shared__ _Float16 Ks[64][64];     // K tile [t][d], XOR-swizzled groups
  __shared__ _Float16 Vt[64][64];     // V^T tile [d][t], XOR-swizzled
  __shared__ _Float16 Ps[4][16][72];  // per-wave P[h][t]
  int tid = threadIdx.x;
  int lane = tid & 63, w = tid >> 6, ln = lane & 15, q4 = lane >> 4;
  int idx = 1023 - (int)blockIdx.x;   // longest chunks first
  int c = idx >> 1, b = idx & 1;
  int s0 = c * 4;
  int s = s0 + w;
  size_t bS = (size_t)b * S_LEN;

  const _Float16* qp = Qb + (bS + s) * DIM + ln * 64 + q4 * 8;
  halfx8 bq0 = *(const halfx8*)qp, bq1 = *(const halfx8*)(qp + 32);

  float m_run = -1e30f, l_run = 0.f;
  floatx4 oacc[4] = {};
  int rr = lane >> 3, gg = (lane & 7) ^ rr;
  const _Float16* kgp = kb + (bS + w * 16 + rr) * 64 + gg * 8;
  const _Float16* vgp = vtb + ((size_t)b * 64 + w * 16 + rr) * S_LEN + gg * 8;
  int swk0 = (q4 ^ (ln & 7)) * 8;
  int swk1 = ((q4 + 4) ^ (ln & 7)) * 8;
  _Float16* Pw = &Ps[w][0][0];
  int nt = (s0 >> 6) + 1;

  for (int it = 0; it < nt; ++it) {
    int t0 = it << 6;
    __syncthreads();
    gll16(kgp + (size_t)t0 * 64,        &Ks[w * 16][0]);
    gll16(kgp + (size_t)t0 * 64 + 512,  &Ks[w * 16 + 8][0]);
    gll16(vgp + t0,                     &Vt[w * 16][0]);
    gll16(vgp + t0 + (size_t)8 * S_LEN, &Vt[w * 16 + 8][0]);
    __syncthreads();

    // S^T = K Q^T (log2 domain already): frag tf rows t=tf*16+ln
    floatx4 sf[4];
#pragma unroll
    for (int tf = 0; tf < 4; ++tf) {
      halfx8 ak0 = *(const halfx8*)&Ks[tf * 16 + ln][swk0];
      halfx8 ak1 = *(const halfx8*)&Ks[tf * 16 + ln][swk1];
      floatx4 z = {};
      z = mfma16(ak0, bq0, z);
      sf[tf] = mfma16(ak1, bq1, z);
    }
    if (it == nt - 1) {  // causal mask (earlier tiles provably all t <= s)
#pragma unroll
      for (int tf = 0; tf < 4; ++tf)
#pragma unroll
        for (int i = 0; i < 4; ++i) {
          int t = t0 + tf * 16 + q4 * 4 + i;
          if (t > s) sf[tf][i] = -1e30f;
        }
    }
    float tm = fmaxf(fmaxf(sf[0][0], sf[0][1]), fmaxf(sf[0][2], sf[0][3]));
#pragma unroll
    for (int tf = 1; tf < 4; ++tf)
      tm = fmaxf(tm, fmaxf(fmaxf(sf[tf][0], sf[tf][1]),
                           fmaxf(sf[tf][2], sf[tf][3])));
    tm = fmaxf(tm, __shfl_xor(tm, 16));
    tm = fmaxf(tm, __shfl_xor(tm, 32));
    float mn = fmaxf(m_run, tm);
    float alpha = exp2f(m_run - mn);
    m_run = mn;
    float rs = 0.f;
#pragma unroll
    for (int tf = 0; tf < 4; ++tf) {
      float p0 = exp2f(sf[tf][0] - mn), p1 = exp2f(sf[tf][1] - mn);
      float p2 = exp2f(sf[tf][2] - mn), p3 = exp2f(sf[tf][3] - mn);
      rs += (p0 + p1) + (p2 + p3);
      halfx4 pk;
      pk[0] = (_Float16)p0; pk[1] = (_Float16)p1;
      pk[2] = (_Float16)p2; pk[3] = (_Float16)p3;
      *(halfx4*)&Pw[ln * 72 + tf * 16 + q4 * 4] = pk;
    }
    rs += __shfl_xor(rs, 16);
    rs += __shfl_xor(rs, 32);
    l_run = l_run * alpha + rs;
    halfx8 bp0 = *(const halfx8*)&Pw[ln * 72 + q4 * 8];
    halfx8 bp1 = *(const halfx8*)&Pw[ln * 72 + 32 + q4 * 8];
#pragma unroll
    for (int n2 = 0; n2 < 4; ++n2) {
      halfx8 av0 = *(const halfx8*)&Vt[n2 * 16 + ln][swk0];
      halfx8 av1 = *(const halfx8*)&Vt[n2 * 16 + ln][swk1];
#pragma unroll
      for (int i = 0; i < 4; ++i) oacc[n2][i] *= alpha;
      oacc[n2] = mfma16(av0, bp0, oacc[n2]);
      oacc[n2] = mfma16(av1, bp1, oacc[n2]);
    }
  }
  // epilogue: O^T frag n2: h=ln, d=n2*16+q4*4+i
  float inv = 1.0f / l_run;
#pragma unroll
  for (int n2 = 0; n2 < 4; ++n2) {
    halfx4 o;
#pragma unroll
    for (int i = 0; i < 4; ++i) o[i] = (_Float16)(oacc[n2][i] * inv);
    *(halfx4*)(aob + (bS + s) * DIM + ln * 64 + n2 * 16 + q4 * 4) = o;
  }
}

extern "C" void kernel_launch(void* const* d_in, const int* in_sizes, int n_in,
                              void* d_out, int out_size, void* d_ws,
                              size_t ws_size, hipStream_t stream) {
  const float* x    = (const float*)d_in[0];
  const float* wqkv = (const float*)d_in[1];
  const float* bqkv = (const float*)d_in[2];
  const float* wout = (const float*)d_in[3];
  const float* bout = (const float*)d_in[4];
  float* out = (float*)d_out;
  char* ws = (char*)d_ws;
  _Float16* xb    = (_Float16*)(ws);                               // 8 MB
  _Float16* qb    = (_Float16*)(ws + (8u << 20));                  // 8 MB
  _Float16* aob   = (_Float16*)(ws + (16u << 20));                 // 8 MB
  _Float16* kb    = (_Float16*)(ws + (24u << 20));                 // 512 KB
  _Float16* vtb   = (_Float16*)(ws + (24u << 20) + (512u << 10));  // 512 KB
  _Float16* wcomb = (_Float16*)(ws + (25u << 20));                 // 2.25 MB
  _Float16* woutb = (_Float16*)(ws + (27u << 20) + (512u << 10));  // 2 MB
  float*    bcomb = (float*)(ws + (29u << 20) + (512u << 10));     // 4.6 KB

  hipLaunchKernelGGL(prep_all, dim3(6656), dim3(256), 0, stream,
                     x, wqkv, bqkv, wout, xb, wcomb, woutb, bcomb);
  hipLaunchKernelGGL((gemm_big<0>), dim3(64, 9), dim3(256), 0, stream,
                     xb, wcomb, bcomb, (void*)qb, kb, vtb);
  hipLaunchKernelGGL(flash_attn5, dim3(1024), dim3(256), 0, stream,
                     qb, kb, vtb, aob);
  hipLaunchKernelGGL((gemm_big<1>), dim3(64, 8), dim3(256), 0, stream,
                     aob, woutb, bout, (void*)out, nullptr, nullptr);
}